// Round 3
// baseline (420.489 us; speedup 1.0000x reference)
//
#include <hip/hip_runtime.h>
#include <cstdint>
#include <cstddef>

typedef unsigned short u16;
typedef short bf16x8 __attribute__((ext_vector_type(8)));
typedef float f32x4 __attribute__((ext_vector_type(4)));

#define NBATCH 2
#define NS 2048
#define NDIM 1024
#define NH 16
#define NHD 64

__device__ __forceinline__ u16 f2b(float f) {
  union { float f; unsigned u; } x; x.f = f;
  return (u16)((x.u + 0x7fffu + ((x.u >> 16) & 1u)) >> 16);
}

// ---------------- f32 -> bf16 conversion (vectorized) ----------------
__global__ void cvt_bf16(const float* __restrict__ s, u16* __restrict__ d, int n) {
  int i = (blockIdx.x * blockDim.x + threadIdx.x) * 4;
  if (i >= n) return;
  float4 v = *reinterpret_cast<const float4*>(s + i);
  ushort4 o;
  o.x = f2b(v.x); o.y = f2b(v.y); o.z = f2b(v.z); o.w = f2b(v.w);
  *reinterpret_cast<ushort4*>(d + i) = o;
}

// ---------------- GEMM: C[m,n] = sum_k A[m,k] * Bt[n,k] ----------------
// A: (M, 1024) bf16 row-major. Bt: (N, 1024) bf16 row-major.
// MODE 0: store f32 to Cf (row-major M x 1024)            [output proj]
// MODE 1: RoPE epilogue, bf16 store, (b,h,s,d) layout     [q, k]
// MODE 3: A=weight,Bt=x (swapped): C = proj^T; bf16 store (b,h,d,s) [v^T]
template<int MODE>
__global__ __launch_bounds__(256, 2)
void gemm_bt(const u16* __restrict__ A, const u16* __restrict__ Bt,
             float* __restrict__ Cf, u16* __restrict__ Cb,
             const float* __restrict__ cosp, const float* __restrict__ sinp) {
  __shared__ __align__(16) u16 sA[128 * 32];
  __shared__ __align__(16) u16 sB[128 * 32];
  const int lane = threadIdx.x & 63;
  const int wid  = threadIdx.x >> 6;
  const int wm = wid >> 1, wn = wid & 1;
  const int tm = blockIdx.x * 128, tn = blockIdx.y * 128;
  const int fr = lane & 15, fq = lane >> 4;
  const int sr = lane >> 2, sc = lane & 3;

  const f32x4 fzero = {0.f, 0.f, 0.f, 0.f};
  f32x4 acc[4][4];
#pragma unroll
  for (int i = 0; i < 4; ++i)
#pragma unroll
    for (int j = 0; j < 4; ++j) acc[i][j] = fzero;

  const u16* gA0 = A  + (size_t)(tm + wid * 32 + sr) * NDIM + sc * 8;
  const u16* gB0 = Bt + (size_t)(tn + wid * 32 + sr) * NDIM + sc * 8;
  u16* lA = &sA[wid * 32 * 32];
  u16* lB = &sB[wid * 32 * 32];

  for (int k0 = 0; k0 < NDIM; k0 += 32) {
    __builtin_amdgcn_global_load_lds((const __attribute__((address_space(1))) unsigned*)(gA0 + k0),
                                     (__attribute__((address_space(3))) unsigned*)lA, 16, 0, 0);
    __builtin_amdgcn_global_load_lds((const __attribute__((address_space(1))) unsigned*)(gA0 + k0 + 16 * NDIM),
                                     (__attribute__((address_space(3))) unsigned*)(lA + 16 * 32), 16, 0, 0);
    __builtin_amdgcn_global_load_lds((const __attribute__((address_space(1))) unsigned*)(gB0 + k0),
                                     (__attribute__((address_space(3))) unsigned*)lB, 16, 0, 0);
    __builtin_amdgcn_global_load_lds((const __attribute__((address_space(1))) unsigned*)(gB0 + k0 + 16 * NDIM),
                                     (__attribute__((address_space(3))) unsigned*)(lB + 16 * 32), 16, 0, 0);
    __syncthreads();

    bf16x8 af[4], bff[4];
#pragma unroll
    for (int i = 0; i < 4; ++i)
      af[i] = *reinterpret_cast<const bf16x8*>(&sA[(wm * 64 + i * 16 + fr) * 32 + fq * 8]);
#pragma unroll
    for (int i = 0; i < 4; ++i)
      bff[i] = *reinterpret_cast<const bf16x8*>(&sB[(wn * 64 + i * 16 + fr) * 32 + fq * 8]);
#pragma unroll
    for (int mi = 0; mi < 4; ++mi)
#pragma unroll
      for (int ni = 0; ni < 4; ++ni)
        acc[mi][ni] = __builtin_amdgcn_mfma_f32_16x16x32_bf16(af[mi], bff[ni], acc[mi][ni], 0, 0, 0);
    __syncthreads();
  }

  // epilogue: C/D layout col = lane&15, row = (lane>>4)*4 + reg  [m89-verified]
#pragma unroll
  for (int mi = 0; mi < 4; ++mi) {
#pragma unroll
    for (int ni = 0; ni < 4; ++ni) {
#pragma unroll
      for (int r = 0; r < 4; ++r) {
        const int row = tm + wm * 64 + mi * 16 + fq * 4 + r;
        const int col = tn + wn * 64 + ni * 16 + fr;
        float val = acc[mi][ni][r];
        if (MODE == 0) {
          Cf[(size_t)row * NDIM + col] = val;
        } else if (MODE == 1) {
          const int b = row >> 11, s = row & (NS - 1);
          const int h = col >> 6,  d = col & 63;
          // RoPE: pair (2i, 2i+1) within head; partner col = col^1 lives in lane^1
          const int fi = d >> 1;
          const float c  = cosp[s * 32 + fi];
          const float sn = sinp[s * 32 + fi];
          const float partner = __shfl_xor(val, 1);
          val = (d & 1) ? (partner * sn + val * c) : (val * c - partner * sn);
          Cb[((size_t)(b * NH + h) * NS + s) * NHD + d] = f2b(val);
        } else {  // MODE 3: row = out-dim (h,d), col = (b,s); store (b,h,d,s)
          const int hh = row >> 6, d = row & 63;
          const int b = col >> 11, s = col & (NS - 1);
          Cb[((size_t)(b * NH + hh) * NHD + d) * NS + s] = f2b(val);
        }
      }
    }
  }
}

// ---------------- causal flash attention ----------------
// Q,K: bf16 (b,h,s,d). Vt: bf16 (b,h,d,s). O: bf16 (b,s,h*64+d).
// grid = (B*H) * (S/64); block = 256 (4 waves); wave w owns 16 q-rows.
// KVBLK = 64 keys/iteration.
__global__ __launch_bounds__(256, 2)
void attn_fwd(const u16* __restrict__ Q, const u16* __restrict__ K,
              const u16* __restrict__ Vt, u16* __restrict__ O) {
  // P tile per wave: 16 q-rows x 64 keys, row padded to 72 u16 (144B) so the
  // b128 A-frag reads hit the uniform 8-access/bank floor (no extra conflict).
  __shared__ __align__(16) u16 p_lds[4][16 * 72];
  const int lane = threadIdx.x & 63;
  const int w = threadIdx.x >> 6;
  const int bh = blockIdx.x >> 5;
  const int qt = 31 - (blockIdx.x & 31);  // longest blocks launch first
  const int q0 = qt * 64 + w * 16;
  const int fr = lane & 15, fq = lane >> 4;
  const size_t baseK = (size_t)bh * NS * NHD;  // (s,d) layout
  const size_t baseV = (size_t)bh * NHD * NS;  // (d,s) layout

  const f32x4 fzero = {0.f, 0.f, 0.f, 0.f};
  // Q fragments (A-operand: row = lane&15, k = (lane>>4)*8 + j (+32))
  bf16x8 aq0 = *reinterpret_cast<const bf16x8*>(&Q[baseK + (size_t)(q0 + fr) * NHD + fq * 8]);
  bf16x8 aq1 = *reinterpret_cast<const bf16x8*>(&Q[baseK + (size_t)(q0 + fr) * NHD + 32 + fq * 8]);

  float m[4], lsum[4];
  f32x4 o[4];
#pragma unroll
  for (int r = 0; r < 4; ++r) { m[r] = -1e30f; lsum[r] = 0.f; }
#pragma unroll
  for (int nb = 0; nb < 4; ++nb) o[nb] = fzero;

  const int nkt = (q0 + 16 + 63) >> 6;  // key tiles of 64, causal bound
  for (int kt = 0; kt < nkt; ++kt) {
    const int key0 = kt * 64;
    float ps[4][4];
    // S = Q K^T  (B-operand: col = key = lane&15, k = d contiguous)
#pragma unroll
    for (int h = 0; h < 4; ++h) {
      const u16* kp = &K[baseK + (size_t)(key0 + h * 16 + fr) * NHD + fq * 8];
      bf16x8 kb0 = *reinterpret_cast<const bf16x8*>(kp);
      bf16x8 kb1 = *reinterpret_cast<const bf16x8*>(kp + 32);
      f32x4 sf = fzero;
      sf = __builtin_amdgcn_mfma_f32_16x16x32_bf16(aq0, kb0, sf, 0, 0, 0);
      sf = __builtin_amdgcn_mfma_f32_16x16x32_bf16(aq1, kb1, sf, 0, 0, 0);
      const int key = key0 + h * 16 + fr;
#pragma unroll
      for (int r = 0; r < 4; ++r)
        ps[h][r] = (key > q0 + fq * 4 + r) ? -1e30f : sf[r] * 0.125f;
    }
    // online softmax: per-lane rows = q0 + fq*4 + r; reduce across 16 key-lanes
#pragma unroll
    for (int r = 0; r < 4; ++r) {
      float rm = fmaxf(fmaxf(ps[0][r], ps[1][r]), fmaxf(ps[2][r], ps[3][r]));
#pragma unroll
      for (int off = 1; off < 16; off <<= 1) rm = fmaxf(rm, __shfl_xor(rm, off));
      const float mn = fmaxf(m[r], rm);
      const float al = __expf(m[r] - mn);
      float rs = 0.f;
#pragma unroll
      for (int h = 0; h < 4; ++h) { ps[h][r] = __expf(ps[h][r] - mn); rs += ps[h][r]; }
#pragma unroll
      for (int off = 1; off < 16; off <<= 1) rs += __shfl_xor(rs, off);
      lsum[r] = lsum[r] * al + rs;
      m[r] = mn;
#pragma unroll
      for (int nb = 0; nb < 4; ++nb) o[nb][r] *= al;
    }
    // P (C-layout) -> LDS -> reload as A-operand fragments. Wave-local:
    // DS ops are in-order within a wave; no __syncthreads (divergent loops).
#pragma unroll
    for (int h = 0; h < 4; ++h)
#pragma unroll
      for (int r = 0; r < 4; ++r)
        p_lds[w][(fq * 4 + r) * 72 + h * 16 + fr] = f2b(ps[h][r]);
    __builtin_amdgcn_wave_barrier();
    asm volatile("s_waitcnt lgkmcnt(0)" ::: "memory");
    // O += P V  over two k=32 chunks; B-operand from transposed V: 16B loads
#pragma unroll
    for (int c = 0; c < 2; ++c) {
      bf16x8 ap = *reinterpret_cast<const bf16x8*>(&p_lds[w][fr * 72 + c * 32 + fq * 8]);
#pragma unroll
      for (int nb = 0; nb < 4; ++nb) {
        bf16x8 bv = *reinterpret_cast<const bf16x8*>(
            &Vt[baseV + (size_t)(nb * 16 + fr) * NS + key0 + c * 32 + fq * 8]);
        o[nb] = __builtin_amdgcn_mfma_f32_16x16x32_bf16(ap, bv, o[nb], 0, 0, 0);
      }
    }
    __builtin_amdgcn_wave_barrier();
  }
  const int b = bh >> 4, h = bh & 15;
#pragma unroll
  for (int nb = 0; nb < 4; ++nb)
#pragma unroll
    for (int r = 0; r < 4; ++r) {
      const int qrow = q0 + fq * 4 + r;
      const int d = nb * 16 + fr;
      O[((size_t)(b * NS + qrow)) * NDIM + h * NHD + d] = f2b(o[nb][r] / lsum[r]);
    }
}

// ---------------- launch ----------------
extern "C" void kernel_launch(void* const* d_in, const int* in_sizes, int n_in,
                              void* d_out, int out_size, void* d_ws, size_t ws_size,
                              hipStream_t stream) {
  const float* x  = (const float*)d_in[0];
  const float* wq = (const float*)d_in[1];
  const float* wk = (const float*)d_in[2];
  const float* wv = (const float*)d_in[3];
  const float* wo = (const float*)d_in[4];
  const float* fc = (const float*)d_in[5];
  const float* fs = (const float*)d_in[6];
  // d_in[7] = mask: implemented as causal predicate, not read.

  // workspace layout (u16 elements)
  u16* xb  = (u16*)d_ws;            // x bf16        (4096x1024)
  u16* wqb = xb  + 4194304;
  u16* wkb = wqb + 1048576;
  u16* wvb = wkb + 1048576;
  u16* wob = wvb + 1048576;
  u16* qw  = wob + 1048576;         // q (b,h,s,d)
  u16* kw  = qw  + 4194304;         // k (b,h,s,d)
  u16* vw  = kw  + 4194304;         // v^T (b,h,d,s)
  u16* aw  = vw  + 4194304;         // attn out (b,s,dim)

  cvt_bf16<<<4096, 256, 0, stream>>>(x,  xb,  4194304);
  cvt_bf16<<<1024, 256, 0, stream>>>(wq, wqb, 1048576);
  cvt_bf16<<<1024, 256, 0, stream>>>(wk, wkb, 1048576);
  cvt_bf16<<<1024, 256, 0, stream>>>(wv, wvb, 1048576);
  cvt_bf16<<<1024, 256, 0, stream>>>(wo, wob, 1048576);

  dim3 g(32, 8);   // M/128 x N/128
  gemm_bt<1><<<g, 256, 0, stream>>>(xb, wqb, nullptr, qw, fc, fs);
  gemm_bt<1><<<g, 256, 0, stream>>>(xb, wkb, nullptr, kw, fc, fs);
  // V^T: swapped operands -> C = (x wv^T)^T, M=1024, N=4096
  dim3 gv(8, 32);
  gemm_bt<3><<<gv, 256, 0, stream>>>(wvb, xb, nullptr, vw, nullptr, nullptr);

  attn_fwd<<<NBATCH * NH * (NS / 64), 256, 0, stream>>>(qw, kw, vw, aw);

  gemm_bt<0><<<g, 256, 0, stream>>>(aw, wob, (float*)d_out, nullptr, nullptr, nullptr);
}

// Round 4
// 397.059 us; speedup vs baseline: 1.0590x; 1.0590x over previous
//
#include <hip/hip_runtime.h>
#include <cstdint>
#include <cstddef>

typedef unsigned short u16;
typedef short bf16x8 __attribute__((ext_vector_type(8)));
typedef float f32x4 __attribute__((ext_vector_type(4)));

#define NBATCH 2
#define NS 2048
#define NDIM 1024
#define NH 16
#define NHD 64

__device__ __forceinline__ u16 f2b(float f) {
  union { float f; unsigned u; } x; x.f = f;
  return (u16)((x.u + 0x7fffu + ((x.u >> 16) & 1u)) >> 16);
}

// ---------------- fused f32 -> bf16 conversion (all 5 tensors) ----------------
__global__ void cvt_all(const float* __restrict__ x,  const float* __restrict__ wq,
                        const float* __restrict__ wk, const float* __restrict__ wv,
                        const float* __restrict__ wo,
                        u16* __restrict__ xb,  u16* __restrict__ wqb,
                        u16* __restrict__ wkb, u16* __restrict__ wvb,
                        u16* __restrict__ wob) {
  int i4 = (blockIdx.x * blockDim.x + threadIdx.x) * 4;
  const float* s; u16* d; int off;
  if (i4 < 4194304) { s = x; d = xb; off = i4; }
  else {
    int j = i4 - 4194304;
    int seg = j >> 20; off = j & 1048575;
    s = seg == 0 ? wq : seg == 1 ? wk : seg == 2 ? wv : wo;
    d = seg == 0 ? wqb : seg == 1 ? wkb : seg == 2 ? wvb : wob;
  }
  float4 v = *reinterpret_cast<const float4*>(s + off);
  ushort4 o;
  o.x = f2b(v.x); o.y = f2b(v.y); o.z = f2b(v.z); o.w = f2b(v.w);
  *reinterpret_cast<ushort4*>(d + off) = o;
}

// ---------------- GEMM: C[m,n] = sum_k A[m,k] * Bt[n,k] ----------------
// MODE 0: store f32 to Cf (row-major M x 1024)            [output proj]
// MODE 3: A=weight,Bt=x (swapped): C = proj^T; bf16 store (b,h,d,s) [v^T]
template<int MODE>
__global__ __launch_bounds__(256, 2)
void gemm_bt(const u16* __restrict__ A, const u16* __restrict__ Bt,
             float* __restrict__ Cf, u16* __restrict__ Cb) {
  __shared__ __align__(16) u16 sA[128 * 32];
  __shared__ __align__(16) u16 sB[128 * 32];
  const int lane = threadIdx.x & 63;
  const int wid  = threadIdx.x >> 6;
  const int wm = wid >> 1, wn = wid & 1;
  const int tm = blockIdx.x * 128, tn = blockIdx.y * 128;
  const int fr = lane & 15, fq = lane >> 4;
  const int sr = lane >> 2, sc = lane & 3;

  const f32x4 fzero = {0.f, 0.f, 0.f, 0.f};
  f32x4 acc[4][4];
#pragma unroll
  for (int i = 0; i < 4; ++i)
#pragma unroll
    for (int j = 0; j < 4; ++j) acc[i][j] = fzero;

  const u16* gA0 = A  + (size_t)(tm + wid * 32 + sr) * NDIM + sc * 8;
  const u16* gB0 = Bt + (size_t)(tn + wid * 32 + sr) * NDIM + sc * 8;
  u16* lA = &sA[wid * 32 * 32];
  u16* lB = &sB[wid * 32 * 32];

  for (int k0 = 0; k0 < NDIM; k0 += 32) {
    __builtin_amdgcn_global_load_lds((const __attribute__((address_space(1))) unsigned*)(gA0 + k0),
                                     (__attribute__((address_space(3))) unsigned*)lA, 16, 0, 0);
    __builtin_amdgcn_global_load_lds((const __attribute__((address_space(1))) unsigned*)(gA0 + k0 + 16 * NDIM),
                                     (__attribute__((address_space(3))) unsigned*)(lA + 16 * 32), 16, 0, 0);
    __builtin_amdgcn_global_load_lds((const __attribute__((address_space(1))) unsigned*)(gB0 + k0),
                                     (__attribute__((address_space(3))) unsigned*)lB, 16, 0, 0);
    __builtin_amdgcn_global_load_lds((const __attribute__((address_space(1))) unsigned*)(gB0 + k0 + 16 * NDIM),
                                     (__attribute__((address_space(3))) unsigned*)(lB + 16 * 32), 16, 0, 0);
    __syncthreads();

    bf16x8 af[4], bff[4];
#pragma unroll
    for (int i = 0; i < 4; ++i)
      af[i] = *reinterpret_cast<const bf16x8*>(&sA[(wm * 64 + i * 16 + fr) * 32 + fq * 8]);
#pragma unroll
    for (int i = 0; i < 4; ++i)
      bff[i] = *reinterpret_cast<const bf16x8*>(&sB[(wn * 64 + i * 16 + fr) * 32 + fq * 8]);
#pragma unroll
    for (int mi = 0; mi < 4; ++mi)
#pragma unroll
      for (int ni = 0; ni < 4; ++ni)
        acc[mi][ni] = __builtin_amdgcn_mfma_f32_16x16x32_bf16(af[mi], bff[ni], acc[mi][ni], 0, 0, 0);
    __syncthreads();
  }

#pragma unroll
  for (int mi = 0; mi < 4; ++mi) {
#pragma unroll
    for (int ni = 0; ni < 4; ++ni) {
#pragma unroll
      for (int r = 0; r < 4; ++r) {
        const int row = tm + wm * 64 + mi * 16 + fq * 4 + r;
        const int col = tn + wn * 64 + ni * 16 + fr;
        float val = acc[mi][ni][r];
        if (MODE == 0) {
          Cf[(size_t)row * NDIM + col] = val;
        } else {  // MODE 3: row = out-dim (h,d), col = (b,s); store (b,h,d,s)
          const int hh = row >> 6, d = row & 63;
          const int b = col >> 11, s = col & (NS - 1);
          Cb[((size_t)(b * NH + hh) * NHD + d) * NS + s] = f2b(val);
        }
      }
    }
  }
}

// ---------------- fused Q+K projection with RoPE epilogue ----------------
// grid (32, 16): blockIdx.y < 8 -> Q, else K. Same GEMM core as gemm_bt.
__global__ __launch_bounds__(256, 2)
void gemm_qk(const u16* __restrict__ A, const u16* __restrict__ WQ, const u16* __restrict__ WK,
             u16* __restrict__ Qo, u16* __restrict__ Ko,
             const float* __restrict__ cosp, const float* __restrict__ sinp) {
  __shared__ __align__(16) u16 sA[128 * 32];
  __shared__ __align__(16) u16 sB[128 * 32];
  const int lane = threadIdx.x & 63;
  const int wid  = threadIdx.x >> 6;
  const int wm = wid >> 1, wn = wid & 1;
  const int tnG = blockIdx.y * 128;
  const int which = tnG >> 10;
  const u16* Bt = which ? WK : WQ;
  u16* Cb = which ? Ko : Qo;
  const int tm = blockIdx.x * 128, tn = tnG & 1023;
  const int fr = lane & 15, fq = lane >> 4;
  const int sr = lane >> 2, sc = lane & 3;

  const f32x4 fzero = {0.f, 0.f, 0.f, 0.f};
  f32x4 acc[4][4];
#pragma unroll
  for (int i = 0; i < 4; ++i)
#pragma unroll
    for (int j = 0; j < 4; ++j) acc[i][j] = fzero;

  const u16* gA0 = A  + (size_t)(tm + wid * 32 + sr) * NDIM + sc * 8;
  const u16* gB0 = Bt + (size_t)(tn + wid * 32 + sr) * NDIM + sc * 8;
  u16* lA = &sA[wid * 32 * 32];
  u16* lB = &sB[wid * 32 * 32];

  for (int k0 = 0; k0 < NDIM; k0 += 32) {
    __builtin_amdgcn_global_load_lds((const __attribute__((address_space(1))) unsigned*)(gA0 + k0),
                                     (__attribute__((address_space(3))) unsigned*)lA, 16, 0, 0);
    __builtin_amdgcn_global_load_lds((const __attribute__((address_space(1))) unsigned*)(gA0 + k0 + 16 * NDIM),
                                     (__attribute__((address_space(3))) unsigned*)(lA + 16 * 32), 16, 0, 0);
    __builtin_amdgcn_global_load_lds((const __attribute__((address_space(1))) unsigned*)(gB0 + k0),
                                     (__attribute__((address_space(3))) unsigned*)lB, 16, 0, 0);
    __builtin_amdgcn_global_load_lds((const __attribute__((address_space(1))) unsigned*)(gB0 + k0 + 16 * NDIM),
                                     (__attribute__((address_space(3))) unsigned*)(lB + 16 * 32), 16, 0, 0);
    __syncthreads();

    bf16x8 af[4], bff[4];
#pragma unroll
    for (int i = 0; i < 4; ++i)
      af[i] = *reinterpret_cast<const bf16x8*>(&sA[(wm * 64 + i * 16 + fr) * 32 + fq * 8]);
#pragma unroll
    for (int i = 0; i < 4; ++i)
      bff[i] = *reinterpret_cast<const bf16x8*>(&sB[(wn * 64 + i * 16 + fr) * 32 + fq * 8]);
#pragma unroll
    for (int mi = 0; mi < 4; ++mi)
#pragma unroll
      for (int ni = 0; ni < 4; ++ni)
        acc[mi][ni] = __builtin_amdgcn_mfma_f32_16x16x32_bf16(af[mi], bff[ni], acc[mi][ni], 0, 0, 0);
    __syncthreads();
  }

#pragma unroll
  for (int mi = 0; mi < 4; ++mi) {
#pragma unroll
    for (int ni = 0; ni < 4; ++ni) {
#pragma unroll
      for (int r = 0; r < 4; ++r) {
        const int row = tm + wm * 64 + mi * 16 + fq * 4 + r;
        const int col = tn + wn * 64 + ni * 16 + fr;
        float val = acc[mi][ni][r];
        const int b = row >> 11, s = row & (NS - 1);
        const int h = col >> 6,  d = col & 63;
        // RoPE: pair (2i, 2i+1); partner col = col^1 lives in lane^1
        const int fi = d >> 1;
        const float c  = cosp[s * 32 + fi];
        const float sn = sinp[s * 32 + fi];
        const float partner = __shfl_xor(val, 1);
        val = (d & 1) ? (partner * sn + val * c) : (val * c - partner * sn);
        Cb[((size_t)(b * NH + h) * NS + s) * NHD + d] = f2b(val);
      }
    }
  }
}

// ---------------- causal flash attention (register-pipelined) ----------------
// Q,K: bf16 (b,h,s,d). Vt: bf16 (b,h,d,s). O: bf16 (b,s,h*64+d).
// grid = (B*H) * (S/64); block = 256 (4 waves); wave w owns 16 q-rows.
// KVBLK = 64. K double-buffered in regs (ping-pong, static indexing);
// Vt loads issued at body start so L2 latency hides under QK+softmax.
__global__ __launch_bounds__(256, 3)
void attn_fwd(const u16* __restrict__ Q, const u16* __restrict__ K,
              const u16* __restrict__ Vt, u16* __restrict__ O) {
  __shared__ __align__(16) u16 p_lds[4][16 * 72];
  const int lane = threadIdx.x & 63;
  const int w = threadIdx.x >> 6;
  const int bh = blockIdx.x >> 5;
  const int qt = 31 - (blockIdx.x & 31);  // longest blocks launch first
  const int q0 = qt * 64 + w * 16;
  const int fr = lane & 15, fq = lane >> 4;
  const size_t baseK = (size_t)bh * NS * NHD;  // (s,d) layout
  const size_t baseV = (size_t)bh * NHD * NS;  // (d,s) layout

  const f32x4 fzero = {0.f, 0.f, 0.f, 0.f};
  bf16x8 aq0 = *reinterpret_cast<const bf16x8*>(&Q[baseK + (size_t)(q0 + fr) * NHD + fq * 8]);
  bf16x8 aq1 = *reinterpret_cast<const bf16x8*>(&Q[baseK + (size_t)(q0 + fr) * NHD + 32 + fq * 8]);

  float m[4], lsum[4];
  f32x4 o[4];
#pragma unroll
  for (int r = 0; r < 4; ++r) { m[r] = -1e30f; lsum[r] = 0.f; }
#pragma unroll
  for (int nb = 0; nb < 4; ++nb) o[nb] = fzero;

  bf16x8 kA0[4], kA1[4], kB0[4], kB1[4];

#define LOADK(K0, K1, kt_) do {                                              \
  _Pragma("unroll")                                                          \
  for (int h = 0; h < 4; ++h) {                                              \
    const u16* kp_ = &K[baseK + (size_t)((kt_) * 64 + h * 16 + fr) * NHD + fq * 8]; \
    K0[h] = *reinterpret_cast<const bf16x8*>(kp_);                           \
    K1[h] = *reinterpret_cast<const bf16x8*>(kp_ + 32);                      \
  }                                                                          \
} while (0)

#define BODY(K0, K1, N0, N1, kt_, PREF, MASKED) do {                         \
  const int key0_ = (kt_) * 64;                                              \
  bf16x8 vt_[8];                                                             \
  _Pragma("unroll")                                                          \
  for (int nb = 0; nb < 4; ++nb) {                                           \
    const u16* vp_ = &Vt[baseV + (size_t)(nb * 16 + fr) * NS + key0_ + fq * 8]; \
    vt_[nb * 2 + 0] = *reinterpret_cast<const bf16x8*>(vp_);                 \
    vt_[nb * 2 + 1] = *reinterpret_cast<const bf16x8*>(vp_ + 32);            \
  }                                                                          \
  if (PREF) LOADK(N0, N1, (kt_) + 1);                                        \
  float ps_[4][4];                                                           \
  _Pragma("unroll")                                                          \
  for (int h = 0; h < 4; ++h) {                                              \
    f32x4 sf_ = fzero;                                                       \
    sf_ = __builtin_amdgcn_mfma_f32_16x16x32_bf16(aq0, K0[h], sf_, 0, 0, 0); \
    sf_ = __builtin_amdgcn_mfma_f32_16x16x32_bf16(aq1, K1[h], sf_, 0, 0, 0); \
    _Pragma("unroll")                                                        \
    for (int r = 0; r < 4; ++r) {                                            \
      float v_ = sf_[r] * 0.125f;                                            \
      if (MASKED) {                                                          \
        const int key_ = key0_ + h * 16 + fr;                                \
        if (key_ > q0 + fq * 4 + r) v_ = -1e30f;                             \
      }                                                                      \
      ps_[h][r] = v_;                                                        \
    }                                                                        \
  }                                                                          \
  _Pragma("unroll")                                                          \
  for (int r = 0; r < 4; ++r) {                                              \
    float rm_ = fmaxf(fmaxf(ps_[0][r], ps_[1][r]), fmaxf(ps_[2][r], ps_[3][r])); \
    _Pragma("unroll")                                                        \
    for (int off = 1; off < 16; off <<= 1) rm_ = fmaxf(rm_, __shfl_xor(rm_, off)); \
    const float mn_ = fmaxf(m[r], rm_);                                      \
    const float al_ = __expf(m[r] - mn_);                                    \
    float rs_ = 0.f;                                                         \
    _Pragma("unroll")                                                        \
    for (int h = 0; h < 4; ++h) { ps_[h][r] = __expf(ps_[h][r] - mn_); rs_ += ps_[h][r]; } \
    _Pragma("unroll")                                                        \
    for (int off = 1; off < 16; off <<= 1) rs_ += __shfl_xor(rs_, off);      \
    lsum[r] = lsum[r] * al_ + rs_;                                           \
    m[r] = mn_;                                                              \
    _Pragma("unroll")                                                        \
    for (int nb = 0; nb < 4; ++nb) o[nb][r] *= al_;                          \
  }                                                                          \
  _Pragma("unroll")                                                          \
  for (int h = 0; h < 4; ++h)                                                \
    _Pragma("unroll")                                                        \
    for (int r = 0; r < 4; ++r)                                              \
      p_lds[w][(fq * 4 + r) * 72 + h * 16 + fr] = f2b(ps_[h][r]);            \
  __builtin_amdgcn_wave_barrier();                                           \
  asm volatile("s_waitcnt lgkmcnt(0)" ::: "memory");                         \
  _Pragma("unroll")                                                          \
  for (int c = 0; c < 2; ++c) {                                              \
    bf16x8 ap_ = *reinterpret_cast<const bf16x8*>(&p_lds[w][fr * 72 + c * 32 + fq * 8]); \
    _Pragma("unroll")                                                        \
    for (int nb = 0; nb < 4; ++nb)                                           \
      o[nb] = __builtin_amdgcn_mfma_f32_16x16x32_bf16(ap_, vt_[nb * 2 + c], o[nb], 0, 0, 0); \
  }                                                                          \
  __builtin_amdgcn_wave_barrier();                                           \
} while (0)

  const int nkt = (q0 + 16 + 63) >> 6;  // total tiles; only tile nkt-1 needs mask
  const int U = nkt - 1;                // unmasked tile count
  int kt = 0;
  LOADK(kA0, kA1, 0);
  for (; kt + 2 <= U; kt += 2) {
    BODY(kA0, kA1, kB0, kB1, kt, 1, 0);
    BODY(kB0, kB1, kA0, kA1, kt + 1, 1, 0);
  }
  if (kt < U) {
    BODY(kA0, kA1, kB0, kB1, kt, 1, 0);
    kt++;
    BODY(kB0, kB1, kA0, kA1, kt, 0, 1);
  } else {
    BODY(kA0, kA1, kB0, kB1, kt, 0, 1);
  }
#undef BODY
#undef LOADK

  const int b = bh >> 4, h = bh & 15;
#pragma unroll
  for (int nb = 0; nb < 4; ++nb)
#pragma unroll
    for (int r = 0; r < 4; ++r) {
      const int qrow = q0 + fq * 4 + r;
      const int d = nb * 16 + fr;
      O[((size_t)(b * NS + qrow)) * NDIM + h * NHD + d] = f2b(o[nb][r] / lsum[r]);
    }
}

// ---------------- launch ----------------
extern "C" void kernel_launch(void* const* d_in, const int* in_sizes, int n_in,
                              void* d_out, int out_size, void* d_ws, size_t ws_size,
                              hipStream_t stream) {
  const float* x  = (const float*)d_in[0];
  const float* wq = (const float*)d_in[1];
  const float* wk = (const float*)d_in[2];
  const float* wv = (const float*)d_in[3];
  const float* wo = (const float*)d_in[4];
  const float* fc = (const float*)d_in[5];
  const float* fs = (const float*)d_in[6];
  // d_in[7] = mask: implemented as causal predicate, not read.

  // workspace layout (u16 elements)
  u16* xb  = (u16*)d_ws;            // x bf16        (4096x1024)
  u16* wqb = xb  + 4194304;
  u16* wkb = wqb + 1048576;
  u16* wvb = wkb + 1048576;
  u16* wob = wvb + 1048576;
  u16* qw  = wob + 1048576;         // q (b,h,s,d)
  u16* kw  = qw  + 4194304;         // k (b,h,s,d)
  u16* vw  = kw  + 4194304;         // v^T (b,h,d,s)
  u16* aw  = vw  + 4194304;         // attn out (b,s,dim)

  cvt_all<<<8192, 256, 0, stream>>>(x, wq, wk, wv, wo, xb, wqb, wkb, wvb, wob);

  gemm_qk<<<dim3(32, 16), 256, 0, stream>>>(xb, wqb, wkb, qw, kw, fc, fs);
  // V^T: swapped operands -> C = (x wv^T)^T, M=1024, N=4096
  gemm_bt<3><<<dim3(8, 32), 256, 0, stream>>>(wvb, xb, nullptr, vw);

  attn_fwd<<<NBATCH * NH * (NS / 64), 256, 0, stream>>>(qw, kw, vw, aw);

  gemm_bt<0><<<dim3(32, 8), 256, 0, stream>>>(aw, wob, (float*)d_out, nullptr);
}

// Round 6
// 255.811 us; speedup vs baseline: 1.6437x; 1.5522x over previous
//
#include <hip/hip_runtime.h>
#include <cstdint>
#include <cstddef>

typedef unsigned short u16;
typedef short bf16x8 __attribute__((ext_vector_type(8)));
typedef float f32x4 __attribute__((ext_vector_type(4)));
typedef float f32x16 __attribute__((ext_vector_type(16)));
typedef unsigned u32x2 __attribute__((ext_vector_type(2)));
typedef unsigned u32x4 __attribute__((ext_vector_type(4)));

#define NBATCH 2
#define NS 2048
#define NDIM 1024
#define NH 16
#define NHD 64

__device__ __forceinline__ u16 f2b(float f) {
  union { float f; unsigned u; } x; x.f = f;
  return (u16)((x.u + 0x7fffu + ((x.u >> 16) & 1u)) >> 16);
}

__device__ __forceinline__ unsigned cvtpk_bf16(float lo, float hi) {
  unsigned r;
  asm("v_cvt_pk_bf16_f32 %0, %1, %2" : "=v"(r) : "v"(lo), "v"(hi));
  return r;
}

// ---------------- fused f32 -> bf16 conversion (all 5 tensors) ----------------
__global__ void cvt_all(const float* __restrict__ x,  const float* __restrict__ wq,
                        const float* __restrict__ wk, const float* __restrict__ wv,
                        const float* __restrict__ wo,
                        u16* __restrict__ xb,  u16* __restrict__ wqb,
                        u16* __restrict__ wkb, u16* __restrict__ wvb,
                        u16* __restrict__ wob) {
  int i4 = (blockIdx.x * blockDim.x + threadIdx.x) * 4;
  const float* s; u16* d; int off;
  if (i4 < 4194304) { s = x; d = xb; off = i4; }
  else {
    int j = i4 - 4194304;
    int seg = j >> 20; off = j & 1048575;
    s = seg == 0 ? wq : seg == 1 ? wk : seg == 2 ? wv : wo;
    d = seg == 0 ? wqb : seg == 1 ? wkb : seg == 2 ? wvb : wob;
  }
  float4 v = *reinterpret_cast<const float4*>(s + off);
  ushort4 o;
  o.x = f2b(v.x); o.y = f2b(v.y); o.z = f2b(v.z); o.w = f2b(v.w);
  *reinterpret_cast<ushort4*>(d + off) = o;
}

// ---------------- GEMM: C[m,n] = sum_k A[m,k] * Bt[n,k] ----------------
// MODE 0: store f32 to Cf (row-major M x 1024)            [output proj]
// MODE 3: A=weight,Bt=x (swapped): C = proj^T; bf16 store (b,h,d,s) [v^T]
template<int MODE>
__global__ __launch_bounds__(256, 2)
void gemm_bt(const u16* __restrict__ A, const u16* __restrict__ Bt,
             float* __restrict__ Cf, u16* __restrict__ Cb) {
  __shared__ __align__(16) u16 sA[128 * 32];
  __shared__ __align__(16) u16 sB[128 * 32];
  const int lane = threadIdx.x & 63;
  const int wid  = threadIdx.x >> 6;
  const int wm = wid >> 1, wn = wid & 1;
  const int tm = blockIdx.x * 128, tn = blockIdx.y * 128;
  const int fr = lane & 15, fq = lane >> 4;
  const int sr = lane >> 2, sc = lane & 3;

  const f32x4 fzero = {0.f, 0.f, 0.f, 0.f};
  f32x4 acc[4][4];
#pragma unroll
  for (int i = 0; i < 4; ++i)
#pragma unroll
    for (int j = 0; j < 4; ++j) acc[i][j] = fzero;

  const u16* gA0 = A  + (size_t)(tm + wid * 32 + sr) * NDIM + sc * 8;
  const u16* gB0 = Bt + (size_t)(tn + wid * 32 + sr) * NDIM + sc * 8;
  u16* lA = &sA[wid * 32 * 32];
  u16* lB = &sB[wid * 32 * 32];

  for (int k0 = 0; k0 < NDIM; k0 += 32) {
    __builtin_amdgcn_global_load_lds((const __attribute__((address_space(1))) unsigned*)(gA0 + k0),
                                     (__attribute__((address_space(3))) unsigned*)lA, 16, 0, 0);
    __builtin_amdgcn_global_load_lds((const __attribute__((address_space(1))) unsigned*)(gA0 + k0 + 16 * NDIM),
                                     (__attribute__((address_space(3))) unsigned*)(lA + 16 * 32), 16, 0, 0);
    __builtin_amdgcn_global_load_lds((const __attribute__((address_space(1))) unsigned*)(gB0 + k0),
                                     (__attribute__((address_space(3))) unsigned*)lB, 16, 0, 0);
    __builtin_amdgcn_global_load_lds((const __attribute__((address_space(1))) unsigned*)(gB0 + k0 + 16 * NDIM),
                                     (__attribute__((address_space(3))) unsigned*)(lB + 16 * 32), 16, 0, 0);
    __syncthreads();

    bf16x8 af[4], bff[4];
#pragma unroll
    for (int i = 0; i < 4; ++i)
      af[i] = *reinterpret_cast<const bf16x8*>(&sA[(wm * 64 + i * 16 + fr) * 32 + fq * 8]);
#pragma unroll
    for (int i = 0; i < 4; ++i)
      bff[i] = *reinterpret_cast<const bf16x8*>(&sB[(wn * 64 + i * 16 + fr) * 32 + fq * 8]);
#pragma unroll
    for (int mi = 0; mi < 4; ++mi)
#pragma unroll
      for (int ni = 0; ni < 4; ++ni)
        acc[mi][ni] = __builtin_amdgcn_mfma_f32_16x16x32_bf16(af[mi], bff[ni], acc[mi][ni], 0, 0, 0);
    __syncthreads();
  }

#pragma unroll
  for (int mi = 0; mi < 4; ++mi) {
#pragma unroll
    for (int ni = 0; ni < 4; ++ni) {
#pragma unroll
      for (int r = 0; r < 4; ++r) {
        const int row = tm + wm * 64 + mi * 16 + fq * 4 + r;
        const int col = tn + wn * 64 + ni * 16 + fr;
        float val = acc[mi][ni][r];
        if (MODE == 0) {
          Cf[(size_t)row * NDIM + col] = val;
        } else {  // MODE 3: row = out-dim (h,d), col = (b,s); store (b,h,d,s)
          const int hh = row >> 6, d = row & 63;
          const int b = col >> 11, s = col & (NS - 1);
          Cb[((size_t)(b * NH + hh) * NHD + d) * NS + s] = f2b(val);
        }
      }
    }
  }
}

// ---------------- fused Q+K projection with RoPE epilogue ----------------
__global__ __launch_bounds__(256, 2)
void gemm_qk(const u16* __restrict__ A, const u16* __restrict__ WQ, const u16* __restrict__ WK,
             u16* __restrict__ Qo, u16* __restrict__ Ko,
             const float* __restrict__ cosp, const float* __restrict__ sinp) {
  __shared__ __align__(16) u16 sA[128 * 32];
  __shared__ __align__(16) u16 sB[128 * 32];
  const int lane = threadIdx.x & 63;
  const int wid  = threadIdx.x >> 6;
  const int wm = wid >> 1, wn = wid & 1;
  const int tnG = blockIdx.y * 128;
  const int which = tnG >> 10;
  const u16* Bt = which ? WK : WQ;
  u16* Cb = which ? Ko : Qo;
  const int tm = blockIdx.x * 128, tn = tnG & 1023;
  const int fr = lane & 15, fq = lane >> 4;
  const int sr = lane >> 2, sc = lane & 3;

  const f32x4 fzero = {0.f, 0.f, 0.f, 0.f};
  f32x4 acc[4][4];
#pragma unroll
  for (int i = 0; i < 4; ++i)
#pragma unroll
    for (int j = 0; j < 4; ++j) acc[i][j] = fzero;

  const u16* gA0 = A  + (size_t)(tm + wid * 32 + sr) * NDIM + sc * 8;
  const u16* gB0 = Bt + (size_t)(tn + wid * 32 + sr) * NDIM + sc * 8;
  u16* lA = &sA[wid * 32 * 32];
  u16* lB = &sB[wid * 32 * 32];

  for (int k0 = 0; k0 < NDIM; k0 += 32) {
    __builtin_amdgcn_global_load_lds((const __attribute__((address_space(1))) unsigned*)(gA0 + k0),
                                     (__attribute__((address_space(3))) unsigned*)lA, 16, 0, 0);
    __builtin_amdgcn_global_load_lds((const __attribute__((address_space(1))) unsigned*)(gA0 + k0 + 16 * NDIM),
                                     (__attribute__((address_space(3))) unsigned*)(lA + 16 * 32), 16, 0, 0);
    __builtin_amdgcn_global_load_lds((const __attribute__((address_space(1))) unsigned*)(gB0 + k0),
                                     (__attribute__((address_space(3))) unsigned*)lB, 16, 0, 0);
    __builtin_amdgcn_global_load_lds((const __attribute__((address_space(1))) unsigned*)(gB0 + k0 + 16 * NDIM),
                                     (__attribute__((address_space(3))) unsigned*)(lB + 16 * 32), 16, 0, 0);
    __syncthreads();

    bf16x8 af[4], bff[4];
#pragma unroll
    for (int i = 0; i < 4; ++i)
      af[i] = *reinterpret_cast<const bf16x8*>(&sA[(wm * 64 + i * 16 + fr) * 32 + fq * 8]);
#pragma unroll
    for (int i = 0; i < 4; ++i)
      bff[i] = *reinterpret_cast<const bf16x8*>(&sB[(wn * 64 + i * 16 + fr) * 32 + fq * 8]);
#pragma unroll
    for (int mi = 0; mi < 4; ++mi)
#pragma unroll
      for (int ni = 0; ni < 4; ++ni)
        acc[mi][ni] = __builtin_amdgcn_mfma_f32_16x16x32_bf16(af[mi], bff[ni], acc[mi][ni], 0, 0, 0);
    __syncthreads();
  }

#pragma unroll
  for (int mi = 0; mi < 4; ++mi) {
#pragma unroll
    for (int ni = 0; ni < 4; ++ni) {
#pragma unroll
      for (int r = 0; r < 4; ++r) {
        const int row = tm + wm * 64 + mi * 16 + fq * 4 + r;
        const int col = tn + wn * 64 + ni * 16 + fr;
        float val = acc[mi][ni][r];
        const int b = row >> 11, s = row & (NS - 1);
        const int h = col >> 6,  d = col & 63;
        const int fi = d >> 1;
        const float c  = cosp[s * 32 + fi];
        const float sn = sinp[s * 32 + fi];
        const float partner = __shfl_xor(val, 1);
        val = (d & 1) ? (partner * sn + val * c) : (val * c - partner * sn);
        Cb[((size_t)(b * NH + h) * NS + s) * NHD + d] = f2b(val);
      }
    }
  }
}

// ---------------- causal flash attention: swapped-QK^T, in-register softmax ----
// Q,K: bf16 (b,h,s,d). Vt: bf16 (b,h,d,s). O: bf16 (b,s,h*64+d).
// Each wave owns 32 q-rows; KVBLK=64. St = mfma32x32x16(K, Q): lane holds
// q-col = lane&31, keys (reg&3)+8*(reg>>2)+4*hi (+32 for acc1). Softmax is
// lane-local (31 fmax/fadd + one shfl_xor(32)). Pt B-frags built in-register
// via cvt_pk_bf16 + permlane32_swap (T12). O^T = mfma(Vt, Pt); transposed to
// row-major via per-wave LDS tile at the end.
__global__ __launch_bounds__(256, 2)
void attn_fwd(const u16* __restrict__ Q, const u16* __restrict__ K,
              const u16* __restrict__ Vt, u16* __restrict__ O) {
  __shared__ __align__(16) u16 t_lds[4][32 * 68];
  const int lane = threadIdx.x & 63;
  const int w = threadIdx.x >> 6;
  const int bh  = blockIdx.x & 31;
  const int grp = 15 - (int)(blockIdx.x >> 5);   // heavy q-tiles first
  const int q0w = grp * 128 + w * 32;
  const int qc = lane & 31, hi = lane >> 5;
  const size_t baseQ = (size_t)bh * NS * NHD;    // (s,d)
  const size_t baseV = (size_t)bh * NHD * NS;    // (d,s)
  const int qrow = q0w + qc;

  bf16x8 qf[4];
#pragma unroll
  for (int s = 0; s < 4; ++s)
    qf[s] = *reinterpret_cast<const bf16x8*>(&Q[baseQ + (size_t)qrow * NHD + s * 16 + hi * 8]);

  f32x16 oA = {}, oB = {};
  float m = -1e30f, l = 0.f;

  const int nkt = (q0w + 95) >> 6;
  for (int kt = 0; kt < nkt; ++kt) {
    const int key0 = kt * 64;
    bf16x8 kf0[4], kf1[4], vf0[4], vf1[4];
#pragma unroll
    for (int s = 0; s < 4; ++s) {
      kf0[s] = *reinterpret_cast<const bf16x8*>(&K[baseQ + (size_t)(key0 + qc) * NHD + s * 16 + hi * 8]);
      kf1[s] = *reinterpret_cast<const bf16x8*>(&K[baseQ + (size_t)(key0 + 32 + qc) * NHD + s * 16 + hi * 8]);
      vf0[s] = *reinterpret_cast<const bf16x8*>(&Vt[baseV + (size_t)qc * NS + key0 + s * 16 + hi * 8]);
      vf1[s] = *reinterpret_cast<const bf16x8*>(&Vt[baseV + (size_t)(32 + qc) * NS + key0 + s * 16 + hi * 8]);
    }
    f32x16 s0 = {}, s1 = {};
#pragma unroll
    for (int s = 0; s < 4; ++s) s0 = __builtin_amdgcn_mfma_f32_32x32x16_bf16(kf0[s], qf[s], s0, 0, 0, 0);
#pragma unroll
    for (int s = 0; s < 4; ++s) s1 = __builtin_amdgcn_mfma_f32_32x32x16_bf16(kf1[s], qf[s], s1, 0, 0, 0);

    float p[32];
#pragma unroll
    for (int r = 0; r < 16; ++r) { p[r] = s0[r] * 0.125f; p[16 + r] = s1[r] * 0.125f; }
    if (kt == nkt - 1) {
#pragma unroll
      for (int i = 0; i < 32; ++i) {
        const int key = key0 + ((i & 3) + 8 * ((i >> 2) & 3) + 4 * hi + 32 * (i >> 4));
        if (key > qrow) p[i] = -1e30f;
      }
    }
    float rm = p[0];
#pragma unroll
    for (int i = 1; i < 32; ++i) rm = fmaxf(rm, p[i]);
    rm = fmaxf(rm, __shfl_xor(rm, 32));
    const float mn = fmaxf(m, rm);
    const float al = __expf(m - mn);
    float rs = 0.f;
#pragma unroll
    for (int i = 0; i < 32; ++i) { p[i] = __expf(p[i] - mn); rs += p[i]; }
    rs += __shfl_xor(rs, 32);
    l = l * al + rs; m = mn;
#pragma unroll
    for (int i = 0; i < 16; ++i) { oA[i] *= al; oB[i] *= al; }

    // Pt B-frag, step s covers keys 16s..16s+15: words from p[8s..8s+7].
    // swap(A0,B0): r0 = w0 (hi0: own p0p1; hi1: partner p4p5)
    //              r1 = w2 (hi0: partner p0p1; hi1: own p4p5)
    bf16x8 pt[4];
#pragma unroll
    for (int s = 0; s < 4; ++s) {
      unsigned A0 = cvtpk_bf16(p[8 * s + 0], p[8 * s + 1]);
      unsigned A1 = cvtpk_bf16(p[8 * s + 2], p[8 * s + 3]);
      unsigned B0 = cvtpk_bf16(p[8 * s + 4], p[8 * s + 5]);
      unsigned B1 = cvtpk_bf16(p[8 * s + 6], p[8 * s + 7]);
      u32x2 r0 = __builtin_amdgcn_permlane32_swap(A0, B0, false, false);
      u32x2 r1 = __builtin_amdgcn_permlane32_swap(A1, B1, false, false);
      u32x4 wds = {r0.x, r1.x, r0.y, r1.y};
      pt[s] = __builtin_bit_cast(bf16x8, wds);
    }
#pragma unroll
    for (int s = 0; s < 4; ++s) oA = __builtin_amdgcn_mfma_f32_32x32x16_bf16(vf0[s], pt[s], oA, 0, 0, 0);
#pragma unroll
    for (int s = 0; s < 4; ++s) oB = __builtin_amdgcn_mfma_f32_32x32x16_bf16(vf1[s], pt[s], oB, 0, 0, 0);
  }

  // epilogue: O^T regs -> LDS [qc][dout] (stride 68) -> coalesced 16B stores
  const float invl = 1.0f / l;
#pragma unroll
  for (int g = 0; g < 2; ++g) {
#pragma unroll
    for (int rq = 0; rq < 4; ++rq) {
      const float v0 = (g ? oB[rq * 4 + 0] : oA[rq * 4 + 0]) * invl;
      const float v1 = (g ? oB[rq * 4 + 1] : oA[rq * 4 + 1]) * invl;
      const float v2 = (g ? oB[rq * 4 + 2] : oA[rq * 4 + 2]) * invl;
      const float v3 = (g ? oB[rq * 4 + 3] : oA[rq * 4 + 3]) * invl;
      unsigned* dst = reinterpret_cast<unsigned*>(&t_lds[w][qc * 68 + g * 32 + rq * 8 + hi * 4]);
      dst[0] = cvtpk_bf16(v0, v1);
      dst[1] = cvtpk_bf16(v2, v3);
    }
  }
  __builtin_amdgcn_wave_barrier();
  asm volatile("s_waitcnt lgkmcnt(0)" ::: "memory");
  const int b = bh >> 4, h = bh & 15;
#pragma unroll
  for (int pass = 0; pass < 4; ++pass) {
    const int qr = pass * 8 + (lane >> 3);
    const int c = lane & 7;
    const unsigned* src = reinterpret_cast<const unsigned*>(&t_lds[w][qr * 68 + c * 8]);
    u32x4 val = {src[0], src[1], src[2], src[3]};
    *reinterpret_cast<u32x4*>(&O[((size_t)(b * NS + q0w + qr)) * NDIM + h * NHD + c * 8]) = val;
  }
}

// ---------------- launch ----------------
extern "C" void kernel_launch(void* const* d_in, const int* in_sizes, int n_in,
                              void* d_out, int out_size, void* d_ws, size_t ws_size,
                              hipStream_t stream) {
  const float* x  = (const float*)d_in[0];
  const float* wq = (const float*)d_in[1];
  const float* wk = (const float*)d_in[2];
  const float* wv = (const float*)d_in[3];
  const float* wo = (const float*)d_in[4];
  const float* fc = (const float*)d_in[5];
  const float* fs = (const float*)d_in[6];
  // d_in[7] = mask: implemented as causal predicate, not read.

  u16* xb  = (u16*)d_ws;            // x bf16 (4096x1024)
  u16* wqb = xb  + 4194304;
  u16* wkb = wqb + 1048576;
  u16* wvb = wkb + 1048576;
  u16* wob = wvb + 1048576;
  u16* qw  = wob + 1048576;         // q (b,h,s,d)
  u16* kw  = qw  + 4194304;         // k (b,h,s,d)
  u16* vw  = kw  + 4194304;         // v^T (b,h,d,s)
  u16* aw  = vw  + 4194304;         // attn out (b,s,dim)

  cvt_all<<<8192, 256, 0, stream>>>(x, wq, wk, wv, wo, xb, wqb, wkb, wvb, wob);

  gemm_qk<<<dim3(32, 16), 256, 0, stream>>>(xb, wqb, wkb, qw, kw, fc, fs);
  gemm_bt<3><<<dim3(8, 32), 256, 0, stream>>>(wvb, xb, nullptr, vw);

  attn_fwd<<<512, 256, 0, stream>>>(qw, kw, vw, aw);

  gemm_bt<0><<<dim3(32, 8), 256, 0, stream>>>(aw, wob, (float*)d_out, nullptr);
}

// Round 10
// 246.103 us; speedup vs baseline: 1.7086x; 1.0394x over previous
//
#include <hip/hip_runtime.h>
#include <cstdint>
#include <cstddef>

typedef unsigned short u16;
typedef short bf16x8 __attribute__((ext_vector_type(8)));
typedef float f32x4 __attribute__((ext_vector_type(4)));
typedef float f32x16 __attribute__((ext_vector_type(16)));
typedef unsigned u32x2 __attribute__((ext_vector_type(2)));
typedef unsigned u32x4 __attribute__((ext_vector_type(4)));

#define NBATCH 2
#define NS 2048
#define NDIM 1024
#define NH 16
#define NHD 64
#define C2 0.18033688f   /* 0.125 * log2(e) */

__device__ __forceinline__ u16 f2b(float f) {
  union { float f; unsigned u; } x; x.f = f;
  return (u16)((x.u + 0x7fffu + ((x.u >> 16) & 1u)) >> 16);
}

__device__ __forceinline__ unsigned cvtpk_bf16(float lo, float hi) {
  unsigned r;
  asm("v_cvt_pk_bf16_f32 %0, %1, %2" : "=v"(r) : "v"(lo), "v"(hi));
  return r;
}

// ---------------- fused f32 -> bf16 conversion (all 5 tensors) ----------------
__global__ void cvt_all(const float* __restrict__ x,  const float* __restrict__ wq,
                        const float* __restrict__ wk, const float* __restrict__ wv,
                        const float* __restrict__ wo,
                        u16* __restrict__ xb,  u16* __restrict__ wqb,
                        u16* __restrict__ wkb, u16* __restrict__ wvb,
                        u16* __restrict__ wob) {
  int i4 = (blockIdx.x * blockDim.x + threadIdx.x) * 4;
  const float* s; u16* d; int off;
  if (i4 < 4194304) { s = x; d = xb; off = i4; }
  else {
    int j = i4 - 4194304;
    int seg = j >> 20; off = j & 1048575;
    s = seg == 0 ? wq : seg == 1 ? wk : seg == 2 ? wv : wo;
    d = seg == 0 ? wqb : seg == 1 ? wkb : seg == 2 ? wvb : wob;
  }
  float4 v = *reinterpret_cast<const float4*>(s + off);
  ushort4 o;
  o.x = f2b(v.x); o.y = f2b(v.y); o.z = f2b(v.z); o.w = f2b(v.w);
  *reinterpret_cast<ushort4*>(d + off) = o;
}

// ---------------- fused Q/K/V^T projection (one launch, 768 blocks) ----------
// grid (32, 24): by<8 -> Q (RoPE), by<16 -> K (RoPE), else V^T (swapped ops).
__global__ __launch_bounds__(256, 2)
void gemm_proj(const u16* __restrict__ xb, const u16* __restrict__ wqb,
               const u16* __restrict__ wkb, const u16* __restrict__ wvb,
               u16* __restrict__ qw, u16* __restrict__ kw, u16* __restrict__ vw,
               const float* __restrict__ cosp, const float* __restrict__ sinp) {
  __shared__ __align__(16) u16 sA[128 * 32];
  __shared__ __align__(16) u16 sB[128 * 32];
  const int by = blockIdx.y;
  const int role = by >> 3;                  // 0=Q 1=K 2=V^T
  const u16* A; const u16* Bt; int tm, tn;
  if (role == 2) { A = wvb; Bt = xb; tm = (by & 7) * 128; tn = blockIdx.x * 128; }
  else { A = xb; Bt = role ? wkb : wqb; tm = blockIdx.x * 128; tn = (by & 7) * 128; }

  const int lane = threadIdx.x & 63;
  const int wid  = threadIdx.x >> 6;
  const int wm = wid >> 1, wn = wid & 1;
  const int fr = lane & 15, fq = lane >> 4;
  const int sr = lane >> 2, sc = lane & 3;

  const f32x4 fzero = {0.f, 0.f, 0.f, 0.f};
  f32x4 acc[4][4];
#pragma unroll
  for (int i = 0; i < 4; ++i)
#pragma unroll
    for (int j = 0; j < 4; ++j) acc[i][j] = fzero;

  const u16* gA0 = A  + (size_t)(tm + wid * 32 + sr) * NDIM + sc * 8;
  const u16* gB0 = Bt + (size_t)(tn + wid * 32 + sr) * NDIM + sc * 8;
  u16* lA = &sA[wid * 32 * 32];
  u16* lB = &sB[wid * 32 * 32];

  for (int k0 = 0; k0 < NDIM; k0 += 32) {
    __builtin_amdgcn_global_load_lds((const __attribute__((address_space(1))) unsigned*)(gA0 + k0),
                                     (__attribute__((address_space(3))) unsigned*)lA, 16, 0, 0);
    __builtin_amdgcn_global_load_lds((const __attribute__((address_space(1))) unsigned*)(gA0 + k0 + 16 * NDIM),
                                     (__attribute__((address_space(3))) unsigned*)(lA + 16 * 32), 16, 0, 0);
    __builtin_amdgcn_global_load_lds((const __attribute__((address_space(1))) unsigned*)(gB0 + k0),
                                     (__attribute__((address_space(3))) unsigned*)lB, 16, 0, 0);
    __builtin_amdgcn_global_load_lds((const __attribute__((address_space(1))) unsigned*)(gB0 + k0 + 16 * NDIM),
                                     (__attribute__((address_space(3))) unsigned*)(lB + 16 * 32), 16, 0, 0);
    __syncthreads();

    bf16x8 af[4], bff[4];
#pragma unroll
    for (int i = 0; i < 4; ++i)
      af[i] = *reinterpret_cast<const bf16x8*>(&sA[(wm * 64 + i * 16 + fr) * 32 + fq * 8]);
#pragma unroll
    for (int i = 0; i < 4; ++i)
      bff[i] = *reinterpret_cast<const bf16x8*>(&sB[(wn * 64 + i * 16 + fr) * 32 + fq * 8]);
#pragma unroll
    for (int mi = 0; mi < 4; ++mi)
#pragma unroll
      for (int ni = 0; ni < 4; ++ni)
        acc[mi][ni] = __builtin_amdgcn_mfma_f32_16x16x32_bf16(af[mi], bff[ni], acc[mi][ni], 0, 0, 0);
    __syncthreads();
  }

  u16* CbR = (role == 1) ? kw : qw;
#pragma unroll
  for (int mi = 0; mi < 4; ++mi) {
#pragma unroll
    for (int ni = 0; ni < 4; ++ni) {
#pragma unroll
      for (int r = 0; r < 4; ++r) {
        const int row = tm + wm * 64 + mi * 16 + fq * 4 + r;
        const int col = tn + wn * 64 + ni * 16 + fr;
        float val = acc[mi][ni][r];
        if (role < 2) {
          const int b = row >> 11, s = row & (NS - 1);
          const int h = col >> 6,  d = col & 63;
          const int fi = d >> 1;
          const float c  = cosp[s * 32 + fi];
          const float sn = sinp[s * 32 + fi];
          const float partner = __shfl_xor(val, 1);
          val = (d & 1) ? (partner * sn + val * c) : (val * c - partner * sn);
          CbR[((size_t)(b * NH + h) * NS + s) * NHD + d] = f2b(val);
        } else {  // V^T: row = (h,d) weight out-dim, col = (b,s); store (b,h,d,s)
          const int hh = row >> 6, d = row & 63;
          const int b = col >> 11, s = col & (NS - 1);
          vw[((size_t)(b * NH + hh) * NHD + d) * NS + s] = f2b(val);
        }
      }
    }
  }
}

// ---------------- output projection: 64x128 tile, 512 blocks --------------
__global__ __launch_bounds__(256, 2)
void gemm_out(const u16* __restrict__ A, const u16* __restrict__ Bt,
              float* __restrict__ Cf) {
  __shared__ __align__(16) u16 sA[64 * 32];
  __shared__ __align__(16) u16 sB[128 * 32];
  const int lane = threadIdx.x & 63;
  const int wid  = threadIdx.x >> 6;
  const int wm = wid >> 1, wn = wid & 1;
  const int tm = blockIdx.x * 64, tn = blockIdx.y * 128;
  const int fr = lane & 15, fq = lane >> 4;
  const int sr = lane >> 2, sc = lane & 3;

  const f32x4 fzero = {0.f, 0.f, 0.f, 0.f};
  f32x4 acc[2][4];
#pragma unroll
  for (int i = 0; i < 2; ++i)
#pragma unroll
    for (int j = 0; j < 4; ++j) acc[i][j] = fzero;

  const u16* gA0 = A  + (size_t)(tm + wid * 16 + sr) * NDIM + sc * 8;   // 16 rows/wave
  const u16* gB0 = Bt + (size_t)(tn + wid * 32 + sr) * NDIM + sc * 8;   // 32 rows/wave
  u16* lA = &sA[wid * 16 * 32];
  u16* lB = &sB[wid * 32 * 32];

  for (int k0 = 0; k0 < NDIM; k0 += 32) {
    __builtin_amdgcn_global_load_lds((const __attribute__((address_space(1))) unsigned*)(gA0 + k0),
                                     (__attribute__((address_space(3))) unsigned*)lA, 16, 0, 0);
    __builtin_amdgcn_global_load_lds((const __attribute__((address_space(1))) unsigned*)(gB0 + k0),
                                     (__attribute__((address_space(3))) unsigned*)lB, 16, 0, 0);
    __builtin_amdgcn_global_load_lds((const __attribute__((address_space(1))) unsigned*)(gB0 + k0 + 16 * NDIM),
                                     (__attribute__((address_space(3))) unsigned*)(lB + 16 * 32), 16, 0, 0);
    __syncthreads();

    bf16x8 af[2], bff[4];
#pragma unroll
    for (int i = 0; i < 2; ++i)
      af[i] = *reinterpret_cast<const bf16x8*>(&sA[(wm * 32 + i * 16 + fr) * 32 + fq * 8]);
#pragma unroll
    for (int i = 0; i < 4; ++i)
      bff[i] = *reinterpret_cast<const bf16x8*>(&sB[(wn * 64 + i * 16 + fr) * 32 + fq * 8]);
#pragma unroll
    for (int mi = 0; mi < 2; ++mi)
#pragma unroll
      for (int ni = 0; ni < 4; ++ni)
        acc[mi][ni] = __builtin_amdgcn_mfma_f32_16x16x32_bf16(af[mi], bff[ni], acc[mi][ni], 0, 0, 0);
    __syncthreads();
  }

#pragma unroll
  for (int mi = 0; mi < 2; ++mi)
#pragma unroll
    for (int ni = 0; ni < 4; ++ni)
#pragma unroll
      for (int r = 0; r < 4; ++r) {
        const int row = tm + wm * 32 + mi * 16 + fq * 4 + r;
        const int col = tn + wn * 64 + ni * 16 + fr;
        Cf[(size_t)row * NDIM + col] = acc[mi][ni][r];
      }
}

// ---------------- causal flash attention: swapped-QK^T + reg pipeline --------
// Each wave owns 32 q-rows; KVBLK=64. K/V for tile kt+1 prefetched into the
// alternate reg buffer, pinned above the tile-kt compute by sched_barrier(0)
// (without the pin, the scheduler sinks loads to use sites — round-4 lesson).
// Softmax in exp2 domain; T13 defer-max skips O-rescale when max growth <= 2^8.
__global__ __launch_bounds__(256, 2)
void attn_fwd(const u16* __restrict__ Q, const u16* __restrict__ K,
              const u16* __restrict__ Vt, u16* __restrict__ O) {
  __shared__ __align__(16) u16 t_lds[4][32 * 68];
  const int lane = threadIdx.x & 63;
  const int w = threadIdx.x >> 6;
  const int bh  = blockIdx.x & 31;
  const int grp = 15 - (int)(blockIdx.x >> 5);   // heavy q-tiles first
  const int q0w = grp * 128 + w * 32;
  const int qc = lane & 31, hi = lane >> 5;
  const size_t baseQ = (size_t)bh * NS * NHD;    // (s,d)
  const size_t baseV = (size_t)bh * NHD * NS;    // (d,s)
  const int qrow = q0w + qc;

  bf16x8 qf[4];
#pragma unroll
  for (int s = 0; s < 4; ++s)
    qf[s] = *reinterpret_cast<const bf16x8*>(&Q[baseQ + (size_t)qrow * NHD + s * 16 + hi * 8]);

  f32x16 oA = {}, oB = {};
  float m = -1e30f, l = 0.f;

  bf16x8 kA0[4], kA1[4], vA0[4], vA1[4];
  bf16x8 kB0[4], kB1[4], vB0[4], vB1[4];

#define LOADKV(K0, K1, V0, V1, kt_) do {                                       \
  const int kp0_ = (kt_) * 64;                                                 \
  _Pragma("unroll")                                                            \
  for (int s = 0; s < 4; ++s) {                                                \
    K0[s] = *reinterpret_cast<const bf16x8*>(&K[baseQ + (size_t)(kp0_ + qc) * NHD + s * 16 + hi * 8]); \
    K1[s] = *reinterpret_cast<const bf16x8*>(&K[baseQ + (size_t)(kp0_ + 32 + qc) * NHD + s * 16 + hi * 8]); \
    V0[s] = *reinterpret_cast<const bf16x8*>(&Vt[baseV + (size_t)qc * NS + kp0_ + s * 16 + hi * 8]); \
    V1[s] = *reinterpret_cast<const bf16x8*>(&Vt[baseV + (size_t)(32 + qc) * NS + kp0_ + s * 16 + hi * 8]); \
  }                                                                            \
} while (0)

#define BODY(K0, K1, V0, V1, NK0, NK1, NV0, NV1, kt_, PREF) do {               \
  if (PREF) LOADKV(NK0, NK1, NV0, NV1, (kt_) + 1);                             \
  __builtin_amdgcn_sched_barrier(0);                                           \
  f32x16 s0_ = {}, s1_ = {};                                                   \
  _Pragma("unroll")                                                            \
  for (int s = 0; s < 4; ++s) s0_ = __builtin_amdgcn_mfma_f32_32x32x16_bf16(K0[s], qf[s], s0_, 0, 0, 0); \
  _Pragma("unroll")                                                            \
  for (int s = 0; s < 4; ++s) s1_ = __builtin_amdgcn_mfma_f32_32x32x16_bf16(K1[s], qf[s], s1_, 0, 0, 0); \
  float p_[32];                                                                \
  _Pragma("unroll")                                                            \
  for (int r = 0; r < 16; ++r) { p_[r] = s0_[r]; p_[16 + r] = s1_[r]; }        \
  if ((kt_) == nkt - 1) {                                                      \
    _Pragma("unroll")                                                          \
    for (int i = 0; i < 32; ++i) {                                             \
      const int key_ = (kt_) * 64 + ((i & 3) + 8 * ((i >> 2) & 3) + 4 * hi + 32 * (i >> 4)); \
      if (key_ > qrow) p_[i] = -1e30f;                                         \
    }                                                                          \
  }                                                                            \
  float rm_ = p_[0];                                                           \
  _Pragma("unroll")                                                            \
  for (int i = 1; i < 32; ++i) rm_ = fmaxf(rm_, p_[i]);                        \
  rm_ = fmaxf(rm_, __shfl_xor(rm_, 32));                                       \
  if (!__all(rm_ - m <= 44.3614f)) {                                           \
    const float mn_ = fmaxf(m, rm_);                                           \
    const float al_ = __builtin_amdgcn_exp2f((m - mn_) * C2);                  \
    m = mn_; l *= al_;                                                         \
    _Pragma("unroll")                                                          \
    for (int i = 0; i < 16; ++i) { oA[i] *= al_; oB[i] *= al_; }               \
  }                                                                            \
  float rs_ = 0.f;                                                             \
  _Pragma("unroll")                                                            \
  for (int i = 0; i < 32; ++i) { p_[i] = __builtin_amdgcn_exp2f((p_[i] - m) * C2); rs_ += p_[i]; } \
  rs_ += __shfl_xor(rs_, 32);                                                  \
  l += rs_;                                                                    \
  bf16x8 pt_[4];                                                               \
  _Pragma("unroll")                                                            \
  for (int s = 0; s < 4; ++s) {                                                \
    unsigned A0_ = cvtpk_bf16(p_[8 * s + 0], p_[8 * s + 1]);                   \
    unsigned A1_ = cvtpk_bf16(p_[8 * s + 2], p_[8 * s + 3]);                   \
    unsigned B0_ = cvtpk_bf16(p_[8 * s + 4], p_[8 * s + 5]);                   \
    unsigned B1_ = cvtpk_bf16(p_[8 * s + 6], p_[8 * s + 7]);                   \
    u32x2 r0_ = __builtin_amdgcn_permlane32_swap(A0_, B0_, false, false);      \
    u32x2 r1_ = __builtin_amdgcn_permlane32_swap(A1_, B1_, false, false);      \
    u32x4 wds_ = {r0_.x, r1_.x, r0_.y, r1_.y};                                 \
    pt_[s] = __builtin_bit_cast(bf16x8, wds_);                                 \
  }                                                                            \
  _Pragma("unroll")                                                            \
  for (int s = 0; s < 4; ++s) oA = __builtin_amdgcn_mfma_f32_32x32x16_bf16(V0[s], pt_[s], oA, 0, 0, 0); \
  _Pragma("unroll")                                                            \
  for (int s = 0; s < 4; ++s) oB = __builtin_amdgcn_mfma_f32_32x32x16_bf16(V1[s], pt_[s], oB, 0, 0, 0); \
} while (0)

  const int nkt = (q0w + 95) >> 6;
  int kt = 0;
  LOADKV(kA0, kA1, vA0, vA1, 0);
  for (; kt + 2 <= nkt; kt += 2) {
    BODY(kA0, kA1, vA0, vA1, kB0, kB1, vB0, vB1, kt, 1);
    BODY(kB0, kB1, vB0, vB1, kA0, kA1, vA0, vA1, kt + 1, (kt + 2 < nkt));
  }
  if (kt < nkt)
    BODY(kA0, kA1, vA0, vA1, kB0, kB1, vB0, vB1, kt, 0);
#undef BODY
#undef LOADKV

  // epilogue: O^T regs -> LDS [qc][dout] (stride 68) -> coalesced 16B stores
  const float invl = 1.0f / l;
#pragma unroll
  for (int g = 0; g < 2; ++g) {
#pragma unroll
    for (int rq = 0; rq < 4; ++rq) {
      const float v0 = (g ? oB[rq * 4 + 0] : oA[rq * 4 + 0]) * invl;
      const float v1 = (g ? oB[rq * 4 + 1] : oA[rq * 4 + 1]) * invl;
      const float v2 = (g ? oB[rq * 4 + 2] : oA[rq * 4 + 2]) * invl;
      const float v3 = (g ? oB[rq * 4 + 3] : oA[rq * 4 + 3]) * invl;
      unsigned* dst = reinterpret_cast<unsigned*>(&t_lds[w][qc * 68 + g * 32 + rq * 8 + hi * 4]);
      dst[0] = cvtpk_bf16(v0, v1);
      dst[1] = cvtpk_bf16(v2, v3);
    }
  }
  __builtin_amdgcn_wave_barrier();
  asm volatile("s_waitcnt lgkmcnt(0)" ::: "memory");
  const int b = bh >> 4, h = bh & 15;
#pragma unroll
  for (int pass = 0; pass < 4; ++pass) {
    const int qr = pass * 8 + (lane >> 3);
    const int c = lane & 7;
    const unsigned* src = reinterpret_cast<const unsigned*>(&t_lds[w][qr * 68 + c * 8]);
    u32x4 val = {src[0], src[1], src[2], src[3]};
    *reinterpret_cast<u32x4*>(&O[((size_t)(b * NS + q0w + qr)) * NDIM + h * NHD + c * 8]) = val;
  }
}

// ---------------- launch ----------------
extern "C" void kernel_launch(void* const* d_in, const int* in_sizes, int n_in,
                              void* d_out, int out_size, void* d_ws, size_t ws_size,
                              hipStream_t stream) {
  const float* x  = (const float*)d_in[0];
  const float* wq = (const float*)d_in[1];
  const float* wk = (const float*)d_in[2];
  const float* wv = (const float*)d_in[3];
  const float* wo = (const float*)d_in[4];
  const float* fc = (const float*)d_in[5];
  const float* fs = (const float*)d_in[6];
  // d_in[7] = mask: implemented as causal predicate, not read.

  u16* xb  = (u16*)d_ws;            // x bf16 (4096x1024)
  u16* wqb = xb  + 4194304;
  u16* wkb = wqb + 1048576;
  u16* wvb = wkb + 1048576;
  u16* wob = wvb + 1048576;
  u16* qw  = wob + 1048576;         // q (b,h,s,d)
  u16* kw  = qw  + 4194304;         // k (b,h,s,d)
  u16* vw  = kw  + 4194304;         // v^T (b,h,d,s)
  u16* aw  = vw  + 4194304;         // attn out (b,s,dim)

  cvt_all<<<8192, 256, 0, stream>>>(x, wq, wk, wv, wo, xb, wqb, wkb, wvb, wob);

  gemm_proj<<<dim3(32, 24), 256, 0, stream>>>(xb, wqb, wkb, wvb, qw, kw, vw, fc, fs);

  attn_fwd<<<512, 256, 0, stream>>>(qw, kw, vw, aw);

  gemm_out<<<dim3(64, 8), 256, 0, stream>>>(aw, wob, (float*)d_out);
}